// Round 3
// baseline (2609.138 us; speedup 1.0000x reference)
//
#include <hip/hip_runtime.h>
#include <math.h>

#define NN 100000        // nodes
#define NE 1600000       // edges
#define MNZ 800000       // nnz per motif
#define NM 13            // motifs
#define SLICE_W 12500    // NN / 8 — dst range owned by each XCD slice
// C_IN = C_OUT = D = 64; K_total = 14*64 = 896; out cols = 13*64 = 832

typedef __attribute__((ext_vector_type(8))) short short8;
typedef __attribute__((ext_vector_type(4))) float floatx4;

__device__ __forceinline__ unsigned short f2bf(float f) {
    unsigned int u = __float_as_uint(f);
    u += 0x7FFFu + ((u >> 16) & 1u);   // round-to-nearest-even
    return (unsigned short)(u >> 16);
}

// ---------------- K1: XW = x @ W_rel  (N x 64 @ 64 x 64, fp32) ----------------
__global__ __launch_bounds__(256) void k_xw(const float* __restrict__ x,
                                            const float* __restrict__ W,
                                            float* __restrict__ out) {
    __shared__ float Wl[64 * 64];
    __shared__ float xl[4][64];
    int t = threadIdx.x;
    for (int s = t; s < 4096; s += 256) Wl[s] = W[s];
    int nl = t >> 6, d = t & 63;
    int n = blockIdx.x * 4 + nl;
    xl[nl][d] = x[n * 64 + d];
    __syncthreads();
    float acc = 0.f;
#pragma unroll
    for (int k = 0; k < 64; ++k) acc = fmaf(xl[nl][k], Wl[k * 64 + d], acc);
    out[n * 64 + d] = acc;
}

// ---------------- CSR build: histogram ----------------------------------------
__global__ __launch_bounds__(256) void k_hist_m(const int* __restrict__ mdst,
                                                int* __restrict__ cnt) {
    int m = blockIdx.y;
    int j = blockIdx.x * 256 + threadIdx.x;
    int d = mdst[(long long)m * MNZ + j];
    atomicAdd(&cnt[m * NN + d], 1);
}

__global__ __launch_bounds__(256) void k_hist_e(const int* __restrict__ ei,
                                                int* __restrict__ cnt) {
    int e = blockIdx.x * 256 + threadIdx.x;
    atomicAdd(&cnt[ei[NE + e]], 1);
}

// ---------------- CSR build: segment allocation (block scan + bump cursor) ----
__global__ __launch_bounds__(256) void k_alloc(const int* __restrict__ cnt,
                                               int* __restrict__ off,
                                               int* __restrict__ fill,
                                               int* __restrict__ cursor, int n) {
    __shared__ int sc[256];
    __shared__ int sbase;
    int m = blockIdx.y;
    int t = threadIdx.x;
    int d = blockIdx.x * 256 + t;
    int c = (d < n) ? cnt[(long long)m * n + d] : 0;
    sc[t] = c;
    __syncthreads();
    for (int s = 1; s < 256; s <<= 1) {
        int add = (t >= s) ? sc[t - s] : 0;
        __syncthreads();
        sc[t] += add;
        __syncthreads();
    }
    int incl = sc[t];
    int excl = incl - c;
    if (t == 255) sbase = atomicAdd(cursor + m, incl);  // incl == block total at t=255
    __syncthreads();
    if (d < n) {
        int o = sbase + excl;
        off[(long long)m * n + d] = o;
        fill[(long long)m * n + d] = o;
    }
}

// ---------------- CSR build: scatter {src,val} entries ------------------------
// XCD-slice partitioned: slice = blockIdx.x & 7 owns dst in [slice*12500, ...).
__global__ __launch_bounds__(256) void k_scat_m(const int* __restrict__ msrc,
                                                const int* __restrict__ mdst,
                                                const float* __restrict__ mval,
                                                int* __restrict__ fill,
                                                int2* __restrict__ sm) {
    int m = blockIdx.y;
    int slice = blockIdx.x & 7;
    long long idx = (long long)m * MNZ + (long long)(blockIdx.x >> 3) * 256 + threadIdx.x;
    int d = mdst[idx];
    if (d / SLICE_W == slice) {
        int p = atomicAdd(&fill[m * NN + d], 1);
        sm[(long long)m * MNZ + p] = make_int2(msrc[idx], __float_as_int(mval[idx]));
    }
}

__global__ __launch_bounds__(256) void k_scat_e(const int* __restrict__ ei,
                                                const float* __restrict__ ew,
                                                int* __restrict__ fill,
                                                int2* __restrict__ se) {
    int slice = blockIdx.x & 7;
    int e = (blockIdx.x >> 3) * 256 + threadIdx.x;
    int d = ei[NE + e];
    if (d / SLICE_W == slice) {
        int p = atomicAdd(&fill[d], 1);
        se[p] = make_int2(ei[e], __float_as_int(ew[e]));
    }
}

// ---------------- K2': edge gather  H[d] = sum w * XW[src]  -------------------
__global__ __launch_bounds__(256) void k_gath_e(const int2* __restrict__ se,
                                                const int* __restrict__ off,
                                                const int* __restrict__ cnt,
                                                const float* __restrict__ XW,
                                                float* __restrict__ H) {
    int sub = threadIdx.x >> 4, l = threadIdx.x & 15;
    int d = blockIdx.x * 16 + sub;
    int o = off[d], c = cnt[d];
    const int2* ep = se + o;
    floatx4 acc = (floatx4)0.f;
    int e = 0;
    for (; e + 1 < c; e += 2) {
        int2 a = ep[e], b = ep[e + 1];
        floatx4 ha = *(const floatx4*)&XW[(long long)a.x * 64 + l * 4];
        floatx4 hb = *(const floatx4*)&XW[(long long)b.x * 64 + l * 4];
        float va = __int_as_float(a.y), vb = __int_as_float(b.y);
#pragma unroll
        for (int q = 0; q < 4; ++q) acc[q] = fmaf(va, ha[q], acc[q]);
#pragma unroll
        for (int q = 0; q < 4; ++q) acc[q] = fmaf(vb, hb[q], acc[q]);
    }
    if (e < c) {
        int2 a = ep[e];
        floatx4 ha = *(const floatx4*)&XW[(long long)a.x * 64 + l * 4];
        float va = __int_as_float(a.y);
#pragma unroll
        for (int q = 0; q < 4; ++q) acc[q] = fmaf(va, ha[q], acc[q]);
    }
    *(floatx4*)&H[(long long)d * 64 + l * 4] = acc;
}

// ---------------- K3: h = h*norm + x@root + bias; Rb chunk0 = bf16(h) ---------
__global__ __launch_bounds__(256) void k_fin(const float* __restrict__ x,
                                             const float* __restrict__ root,
                                             const float* __restrict__ bias,
                                             const int* __restrict__ cnt_e,
                                             float* __restrict__ H,
                                             unsigned short* __restrict__ Rb) {
    __shared__ float Wl[64 * 64];
    __shared__ float xl[4][64];
    int t = threadIdx.x;
    for (int s = t; s < 4096; s += 256) Wl[s] = root[s];
    int nl = t >> 6, d = t & 63;
    int n = blockIdx.x * 4 + nl;
    xl[nl][d] = x[n * 64 + d];
    __syncthreads();
    float acc = 0.f;
#pragma unroll
    for (int k = 0; k < 64; ++k) acc = fmaf(xl[nl][k], Wl[k * 64 + d], acc);
    int dg = cnt_e[n];
    float nm = dg > 0 ? 1.0f / (float)dg : 0.f;
    long long idx = (long long)n * 64 + d;
    float hv = H[idx] * nm + acc + bias[d];
    H[idx] = hv;
    Rb[idx] = f2bf(hv);   // chunk 0 of chunk-major Rb [14][NN][64]
}

// ---------------- K4': motif gather  Rb[m+1][d] = bf16(sum v * H[src]) --------
__global__ __launch_bounds__(256) void k_gath_m(const int2* __restrict__ sm,
                                                const int* __restrict__ off,
                                                const int* __restrict__ cnt,
                                                const float* __restrict__ H,
                                                unsigned short* __restrict__ Rb) {
    int m = blockIdx.y;
    int sub = threadIdx.x >> 4, l = threadIdx.x & 15;
    int d = blockIdx.x * 16 + sub;
    long long mi = (long long)m * NN + d;
    int o = off[mi], c = cnt[mi];
    const int2* ep = sm + (long long)m * MNZ + o;
    floatx4 acc = (floatx4)0.f;
    int e = 0;
    for (; e + 1 < c; e += 2) {
        int2 a = ep[e], b = ep[e + 1];
        floatx4 ha = *(const floatx4*)&H[(long long)a.x * 64 + l * 4];
        floatx4 hb = *(const floatx4*)&H[(long long)b.x * 64 + l * 4];
        float va = __int_as_float(a.y), vb = __int_as_float(b.y);
#pragma unroll
        for (int q = 0; q < 4; ++q) acc[q] = fmaf(va, ha[q], acc[q]);
#pragma unroll
        for (int q = 0; q < 4; ++q) acc[q] = fmaf(vb, hb[q], acc[q]);
    }
    if (e < c) {
        int2 a = ep[e];
        floatx4 ha = *(const floatx4*)&H[(long long)a.x * 64 + l * 4];
        float va = __int_as_float(a.y);
#pragma unroll
        for (int q = 0; q < 4; ++q) acc[q] = fmaf(va, ha[q], acc[q]);
    }
    unsigned int lo = (unsigned int)f2bf(acc[0]) | ((unsigned int)f2bf(acc[1]) << 16);
    unsigned int hi = (unsigned int)f2bf(acc[2]) | ((unsigned int)f2bf(acc[3]) << 16);
    *(uint2*)&Rb[((long long)(m + 1) * NN + d) * 64 + l * 4] = make_uint2(lo, hi);
}

// ---------------- K5: build WT (Wbig^T) in bf16: [832 cols][896 k] ------------
__global__ void k_wt(const float* __restrict__ mW, unsigned short* __restrict__ WT) {
    int n = blockIdx.y;                        // 0..831
    int k = blockIdx.x * 128 + threadIdx.x;    // 0..895
    int i = (n >> 6) + 1;
    int d = n & 63;
    int r = k >> 6;
    int kk = k & 63;
    float v = 0.f;
    if (r != i) {
        int j = (r < i) ? r : r - 1;
        v = mW[((long long)(i - 1) * 832 + (j * 64 + kk)) * 64 + d];
    }
    WT[(long long)n * 896 + k] = f2bf(v);
}

// ---------------- K6: fused GEMM + mw + attention -----------------------------
// 1-D grid, bijective XCD swizzle: each XCD owns a contiguous run of
// (row-tile x 13-motif) pairs with motif innermost -> A tile (Rb chunk rows)
// becomes L2-resident per XCD, HBM-fetched ~once total.
// LDS: Al[128][64], Bl[64][64], XOR-swizzled at 8-ushort granules
// (elem (r,k) at r*64 + ((k>>3 ^ (r&7))<<3) + (k&7)) -> bank-uniform reads.
// waT staged into Bl at the kb==14 mw pass (no separate buffer): 24 KB LDS
// -> 6 blocks/CU.
#define BM 128
#define NTY ((NN + BM - 1) / BM)   // 782
#define GEMM_NWG (NM * NTY)        // 10166

__global__ __launch_bounds__(256) void k_gemm(const unsigned short* __restrict__ Rb,
                                              const unsigned short* __restrict__ WT,
                                              const float* __restrict__ wa,
                                              const float* __restrict__ ba,
                                              const float* __restrict__ mb,
                                              float* __restrict__ out) {
    const int nwg = GEMM_NWG, q = nwg >> 3, r = nwg & 7;   // q=1270, r=6
    int lin = blockIdx.x;
    int xcd = lin & 7, pos = lin >> 3;
    int v = (xcd < r ? xcd * (q + 1) : r * (q + 1) + (xcd - r) * q) + pos;
    int row_t = v / NM;
    int im1 = v - row_t * NM;      // 0..12, motif i = im1+1
    int i = im1 + 1;
    int row0 = row_t * BM;
    int t = threadIdx.x;
    int w = t >> 6;
    int lane = t & 63;
    int quad = lane >> 4;
    int l16 = lane & 15;

    __shared__ __align__(16) unsigned short Al[BM * 64];   // 16 KB
    __shared__ __align__(16) unsigned short Bl[64 * 64];   // 8 KB

    floatx4 acc[2][4];   // c accumulator: [m-tile][n-tile]
    floatx4 mwa[2][4];   // mw accumulator
#pragma unroll
    for (int a = 0; a < 2; ++a)
#pragma unroll
        for (int b = 0; b < 4; ++b) { acc[a][b] = (floatx4)0.f; mwa[a][b] = (floatx4)0.f; }

    // kb 0..13: main K loop (c).  kb==14: mw pass (A chunk r=i, B = wa^T in Bl).
    for (int kb = 0; kb < 15; ++kb) {
        int kchunk = (kb < 14) ? kb : i;
        __syncthreads();
        // stage A: 128 rows x 64 k bf16, 16B copies, XOR-swizzled dst
#pragma unroll
        for (int s = 0; s < 4; ++s) {
            int lin8 = t + s * 256;          // granule index 0..1023
            int rr = lin8 >> 3;              // row 0..127
            int g = lin8 & 7;                // 8-ushort granule 0..7
            int grow = row0 + rr;
            short8 vv = (short8)0;
            if (grow < NN) vv = *(const short8*)&Rb[((long long)kchunk * NN + grow) * 64 + g * 8];
            *(short8*)&Al[rr * 64 + ((g ^ (rr & 7)) << 3)] = vv;
        }
        if (kb < 14) {
            // stage B chunk from WT (bf16): 64 rows x 64 k, 16B copies
#pragma unroll
            for (int s = 0; s < 2; ++s) {
                int lin8 = t + s * 256;      // 0..511
                int n = lin8 >> 3;
                int g = lin8 & 7;
                short8 vv = *(const short8*)&WT[(long long)(im1 * 64 + n) * 896 + kb * 64 + g * 8];
                *(short8*)&Bl[n * 64 + ((g ^ (n & 7)) << 3)] = vv;
            }
        } else {
            // stage wa^T (transpose + f2bf), once per block
            for (int s = t; s < 4096; s += 256) {
                int k = s >> 6, d = s & 63;  // wa[k][d] -> Bl[d][k]
                Bl[d * 64 + (((k >> 3) ^ (d & 7)) << 3) + (k & 7)] = f2bf(wa[s]);
            }
        }
        __syncthreads();
#pragma unroll
        for (int kk = 0; kk < 64; kk += 32) {
            int g0 = (kk >> 3) + quad;
            short8 af[2];
#pragma unroll
            for (int mt = 0; mt < 2; ++mt) {
                int arow = (w * 2 + mt) * 16 + l16;
                af[mt] = *(const short8*)&Al[arow * 64 + ((g0 ^ (arow & 7)) << 3)];
            }
#pragma unroll
            for (int nt = 0; nt < 4; ++nt) {
                int brow = nt * 16 + l16;
                short8 bf = *(const short8*)&Bl[brow * 64 + ((g0 ^ (brow & 7)) << 3)];
                if (kb < 14) {
#pragma unroll
                    for (int mt = 0; mt < 2; ++mt)
                        acc[mt][nt] = __builtin_amdgcn_mfma_f32_16x16x32_bf16(af[mt], bf, acc[mt][nt], 0, 0, 0);
                } else {
#pragma unroll
                    for (int mt = 0; mt < 2; ++mt)
                        mwa[mt][nt] = __builtin_amdgcn_mfma_f32_16x16x32_bf16(af[mt], bf, mwa[mt][nt], 0, 0, 0);
                }
            }
        }
    }

    // epilogue: c += mb, mw += ba; att = sigmoid(sum_d mw*c); out = att*(mw-c)
#pragma unroll
    for (int mt = 0; mt < 2; ++mt) {
        float cv[4][4], mv[4][4];   // [nt][reg]
#pragma unroll
        for (int nt = 0; nt < 4; ++nt) {
            int col = nt * 16 + l16;
            float mbv = mb[im1 * 64 + col];
            float bav = ba[col];
#pragma unroll
            for (int r2 = 0; r2 < 4; ++r2) {
                cv[nt][r2] = acc[mt][nt][r2] + mbv;
                mv[nt][r2] = mwa[mt][nt][r2] + bav;
            }
        }
        int grow_base = row0 + (w * 2 + mt) * 16 + quad * 4;
#pragma unroll
        for (int r2 = 0; r2 < 4; ++r2) {
            float s = 0.f;
#pragma unroll
            for (int nt = 0; nt < 4; ++nt) s += mv[nt][r2] * cv[nt][r2];
            s += __shfl_xor(s, 1);
            s += __shfl_xor(s, 2);
            s += __shfl_xor(s, 4);
            s += __shfl_xor(s, 8);   // full 64-col row sum within the 16-lane quad group
            float att = 1.f / (1.f + __expf(-s));
            int grow = grow_base + r2;
            if (grow < NN) {
#pragma unroll
                for (int nt = 0; nt < 4; ++nt)
                    out[(long long)grow * 832 + im1 * 64 + nt * 16 + l16] = att * (mv[nt][r2] - cv[nt][r2]);
            }
        }
    }
}

// ------------------------------------------------------------------------------
extern "C" void kernel_launch(void* const* d_in, const int* in_sizes, int n_in,
                              void* d_out, int out_size, void* d_ws, size_t ws_size,
                              hipStream_t stream) {
    const float* x    = (const float*)d_in[0];
    const int*   ei   = (const int*)d_in[1];
    const float* ew   = (const float*)d_in[2];
    const int*   msrc = (const int*)d_in[3];
    const int*   mdst = (const int*)d_in[4];
    const float* mval = (const float*)d_in[5];
    const float* Wrel = (const float*)d_in[6];
    const float* root = (const float*)d_in[7];
    const float* bias = (const float*)d_in[8];
    const float* wa   = (const float*)d_in[9];
    const float* ba   = (const float*)d_in[10];
    const float* mW   = (const float*)d_in[11];
    const float* mb   = (const float*)d_in[12];
    float* out = (float*)d_out;

    // workspace layout (~345 MB)
    unsigned short* Rb = (unsigned short*)d_ws;                 // [14][NN][64] bf16 (chunk-major)
    float* H  = (float*)(Rb + (size_t)14 * NN * 64);            // [NN][64] fp32
    float* XW = H + (size_t)NN * 64;                            // [NN][64] fp32
    unsigned short* WT = (unsigned short*)(XW + (size_t)NN * 64); // [832][896] bf16
    int2* sm = (int2*)(WT + (size_t)832 * 896);                 // [13][MNZ] {src,val}
    int2* se = sm + (size_t)NM * MNZ;                           // [NE] {src,w}
    int* cnt_m  = (int*)(se + NE);                              // [13][NN]
    int* cnt_e  = cnt_m + (size_t)NM * NN;                      // [NN]
    int* cursors = cnt_e + NN;                                  // [16]
    int* off_m  = cursors + 16;                                 // [13][NN]
    int* fill_m = off_m + (size_t)NM * NN;                      // [13][NN]
    int* off_e  = fill_m + (size_t)NM * NN;                     // [NN]
    int* fill_e = off_e + NN;                                   // [NN]

    // zero cnt_m + cnt_e + cursors in one shot (contiguous)
    hipMemsetAsync(cnt_m, 0, sizeof(int) * ((size_t)NM * NN + NN + 16), stream);

    k_xw<<<NN / 4, 256, 0, stream>>>(x, Wrel, XW);
    k_hist_m<<<dim3(MNZ / 256, NM), 256, 0, stream>>>(mdst, cnt_m);
    k_hist_e<<<NE / 256, 256, 0, stream>>>(ei, cnt_e);
    k_alloc<<<dim3((NN + 255) / 256, NM), 256, 0, stream>>>(cnt_m, off_m, fill_m, cursors, NN);
    k_alloc<<<dim3((NN + 255) / 256, 1), 256, 0, stream>>>(cnt_e, off_e, fill_e, cursors + NM, NN);
    k_scat_m<<<dim3((MNZ / 256) * 8, NM), 256, 0, stream>>>(msrc, mdst, mval, fill_m, sm);
    k_scat_e<<<(NE / 256) * 8, 256, 0, stream>>>(ei, ew, fill_e, se);
    k_gath_e<<<NN / 16, 256, 0, stream>>>(se, off_e, cnt_e, XW, H);
    k_fin<<<NN / 4, 256, 0, stream>>>(x, root, bias, cnt_e, H, Rb);
    k_gath_m<<<dim3(NN / 16, NM), 256, 0, stream>>>(sm, off_m, cnt_m, H, Rb);
    k_wt<<<dim3(7, 832), 128, 0, stream>>>(mW, WT);
    k_gemm<<<GEMM_NWG, 256, 0, stream>>>(Rb, WT, wa, ba, mb, out);
}

// Round 4
// 2403.176 us; speedup vs baseline: 1.0857x; 1.0857x over previous
//
#include <hip/hip_runtime.h>
#include <math.h>

#define NN 100000        // nodes
#define NE 1600000       // edges
#define MNZ 800000       // nnz per motif
#define NM 13            // motifs
#define SLICE_W 12500    // NN / 8 — dst range owned by each XCD slice
// C_IN = C_OUT = D = 64; K_total = 14*64 = 896; out cols = 13*64 = 832

typedef __attribute__((ext_vector_type(8))) short short8;
typedef __attribute__((ext_vector_type(4))) float floatx4;

__device__ __forceinline__ unsigned short f2bf(float f) {
    unsigned int u = __float_as_uint(f);
    u += 0x7FFFu + ((u >> 16) & 1u);   // round-to-nearest-even
    return (unsigned short)(u >> 16);
}

// ---------------- K1: XW = x @ W_rel  (N x 64 @ 64 x 64, fp32) ----------------
__global__ __launch_bounds__(256) void k_xw(const float* __restrict__ x,
                                            const float* __restrict__ W,
                                            float* __restrict__ out) {
    __shared__ float Wl[64 * 64];
    __shared__ float xl[4][64];
    int t = threadIdx.x;
    for (int s = t; s < 4096; s += 256) Wl[s] = W[s];
    int nl = t >> 6, d = t & 63;
    int n = blockIdx.x * 4 + nl;
    xl[nl][d] = x[n * 64 + d];
    __syncthreads();
    float acc = 0.f;
#pragma unroll
    for (int k = 0; k < 64; ++k) acc = fmaf(xl[nl][k], Wl[k * 64 + d], acc);
    out[n * 64 + d] = acc;
}

// ---------------- CSR build: histogram ----------------------------------------
__global__ __launch_bounds__(256) void k_hist_m(const int* __restrict__ mdst,
                                                int* __restrict__ cnt) {
    int m = blockIdx.y;
    int j = blockIdx.x * 256 + threadIdx.x;
    int d = mdst[(long long)m * MNZ + j];
    atomicAdd(&cnt[m * NN + d], 1);
}

__global__ __launch_bounds__(256) void k_hist_e(const int* __restrict__ ei,
                                                int* __restrict__ cnt) {
    int e = blockIdx.x * 256 + threadIdx.x;
    atomicAdd(&cnt[ei[NE + e]], 1);
}

// ---------------- CSR build: segment allocation (block scan + bump cursor) ----
__global__ __launch_bounds__(256) void k_alloc(const int* __restrict__ cnt,
                                               int* __restrict__ off,
                                               int* __restrict__ fill,
                                               int* __restrict__ cursor, int n) {
    __shared__ int sc[256];
    __shared__ int sbase;
    int m = blockIdx.y;
    int t = threadIdx.x;
    int d = blockIdx.x * 256 + t;
    int c = (d < n) ? cnt[(long long)m * n + d] : 0;
    sc[t] = c;
    __syncthreads();
    for (int s = 1; s < 256; s <<= 1) {
        int add = (t >= s) ? sc[t - s] : 0;
        __syncthreads();
        sc[t] += add;
        __syncthreads();
    }
    int incl = sc[t];
    int excl = incl - c;
    if (t == 255) sbase = atomicAdd(cursor + m, incl);  // incl == block total at t=255
    __syncthreads();
    if (d < n) {
        int o = sbase + excl;
        off[(long long)m * n + d] = o;
        fill[(long long)m * n + d] = o;
    }
}

// ---------------- CSR build: scatter {src,val} entries ------------------------
// XCD-slice partitioned: slice = blockIdx.x & 7 owns dst in [slice*12500, ...).
__global__ __launch_bounds__(256) void k_scat_m(const int* __restrict__ msrc,
                                                const int* __restrict__ mdst,
                                                const float* __restrict__ mval,
                                                int* __restrict__ fill,
                                                int2* __restrict__ sm) {
    int m = blockIdx.y;
    int slice = blockIdx.x & 7;
    long long idx = (long long)m * MNZ + (long long)(blockIdx.x >> 3) * 256 + threadIdx.x;
    int d = mdst[idx];
    if (d / SLICE_W == slice) {
        int p = atomicAdd(&fill[m * NN + d], 1);
        sm[(long long)m * MNZ + p] = make_int2(msrc[idx], __float_as_int(mval[idx]));
    }
}

__global__ __launch_bounds__(256) void k_scat_e(const int* __restrict__ ei,
                                                const float* __restrict__ ew,
                                                int* __restrict__ fill,
                                                int2* __restrict__ se) {
    int slice = blockIdx.x & 7;
    int e = (blockIdx.x >> 3) * 256 + threadIdx.x;
    int d = ei[NE + e];
    if (d / SLICE_W == slice) {
        int p = atomicAdd(&fill[d], 1);
        se[p] = make_int2(ei[e], __float_as_int(ew[e]));
    }
}

// ---------------- K2': edge gather  H[d] = sum w * XW[src]  -------------------
__global__ __launch_bounds__(256) void k_gath_e(const int2* __restrict__ se,
                                                const int* __restrict__ off,
                                                const int* __restrict__ cnt,
                                                const float* __restrict__ XW,
                                                float* __restrict__ H) {
    int sub = threadIdx.x >> 4, l = threadIdx.x & 15;
    int d = blockIdx.x * 16 + sub;
    int o = off[d], c = cnt[d];
    const int2* ep = se + o;
    floatx4 acc = (floatx4)0.f;
    int e = 0;
    for (; e + 1 < c; e += 2) {
        int2 a = ep[e], b = ep[e + 1];
        floatx4 ha = *(const floatx4*)&XW[(long long)a.x * 64 + l * 4];
        floatx4 hb = *(const floatx4*)&XW[(long long)b.x * 64 + l * 4];
        float va = __int_as_float(a.y), vb = __int_as_float(b.y);
#pragma unroll
        for (int q = 0; q < 4; ++q) acc[q] = fmaf(va, ha[q], acc[q]);
#pragma unroll
        for (int q = 0; q < 4; ++q) acc[q] = fmaf(vb, hb[q], acc[q]);
    }
    if (e < c) {
        int2 a = ep[e];
        floatx4 ha = *(const floatx4*)&XW[(long long)a.x * 64 + l * 4];
        float va = __int_as_float(a.y);
#pragma unroll
        for (int q = 0; q < 4; ++q) acc[q] = fmaf(va, ha[q], acc[q]);
    }
    *(floatx4*)&H[(long long)d * 64 + l * 4] = acc;
}

// ---------------- K3: h = h*norm + x@root + bias; Rb chunk0 = bf16(h) ---------
__global__ __launch_bounds__(256) void k_fin(const float* __restrict__ x,
                                             const float* __restrict__ root,
                                             const float* __restrict__ bias,
                                             const int* __restrict__ cnt_e,
                                             float* __restrict__ H,
                                             unsigned short* __restrict__ Rb) {
    __shared__ float Wl[64 * 64];
    __shared__ float xl[4][64];
    int t = threadIdx.x;
    for (int s = t; s < 4096; s += 256) Wl[s] = root[s];
    int nl = t >> 6, d = t & 63;
    int n = blockIdx.x * 4 + nl;
    xl[nl][d] = x[n * 64 + d];
    __syncthreads();
    float acc = 0.f;
#pragma unroll
    for (int k = 0; k < 64; ++k) acc = fmaf(xl[nl][k], Wl[k * 64 + d], acc);
    int dg = cnt_e[n];
    float nm = dg > 0 ? 1.0f / (float)dg : 0.f;
    long long idx = (long long)n * 64 + d;
    float hv = H[idx] * nm + acc + bias[d];
    H[idx] = hv;
    Rb[idx] = f2bf(hv);   // chunk 0 of chunk-major Rb [14][NN][64]
}

// ---------------- K4': motif gather  Rb[m+1][d] = bf16(sum v * H[src]) --------
__global__ __launch_bounds__(256) void k_gath_m(const int2* __restrict__ sm,
                                                const int* __restrict__ off,
                                                const int* __restrict__ cnt,
                                                const float* __restrict__ H,
                                                unsigned short* __restrict__ Rb) {
    int m = blockIdx.y;
    int sub = threadIdx.x >> 4, l = threadIdx.x & 15;
    int d = blockIdx.x * 16 + sub;
    long long mi = (long long)m * NN + d;
    int o = off[mi], c = cnt[mi];
    const int2* ep = sm + (long long)m * MNZ + o;
    floatx4 acc = (floatx4)0.f;
    int e = 0;
    for (; e + 1 < c; e += 2) {
        int2 a = ep[e], b = ep[e + 1];
        floatx4 ha = *(const floatx4*)&H[(long long)a.x * 64 + l * 4];
        floatx4 hb = *(const floatx4*)&H[(long long)b.x * 64 + l * 4];
        float va = __int_as_float(a.y), vb = __int_as_float(b.y);
#pragma unroll
        for (int q = 0; q < 4; ++q) acc[q] = fmaf(va, ha[q], acc[q]);
#pragma unroll
        for (int q = 0; q < 4; ++q) acc[q] = fmaf(vb, hb[q], acc[q]);
    }
    if (e < c) {
        int2 a = ep[e];
        floatx4 ha = *(const floatx4*)&H[(long long)a.x * 64 + l * 4];
        float va = __int_as_float(a.y);
#pragma unroll
        for (int q = 0; q < 4; ++q) acc[q] = fmaf(va, ha[q], acc[q]);
    }
    unsigned int lo = (unsigned int)f2bf(acc[0]) | ((unsigned int)f2bf(acc[1]) << 16);
    unsigned int hi = (unsigned int)f2bf(acc[2]) | ((unsigned int)f2bf(acc[3]) << 16);
    *(uint2*)&Rb[((long long)(m + 1) * NN + d) * 64 + l * 4] = make_uint2(lo, hi);
}

// ---------------- K5: build WT (Wbig^T) in bf16: [832 cols][896 k] ------------
__global__ void k_wt(const float* __restrict__ mW, unsigned short* __restrict__ WT) {
    int n = blockIdx.y;                        // 0..831
    int k = blockIdx.x * 128 + threadIdx.x;    // 0..895
    int i = (n >> 6) + 1;
    int d = n & 63;
    int r = k >> 6;
    int kk = k & 63;
    float v = 0.f;
    if (r != i) {
        int j = (r < i) ? r : r - 1;
        v = mW[((long long)(i - 1) * 832 + (j * 64 + kk)) * 64 + d];
    }
    WT[(long long)n * 896 + k] = f2bf(v);
}

// ---------------- K5b: waTb[d][k] = bf16(wa[k][d])  (64x64) -------------------
__global__ __launch_bounds__(256) void k_wat(const float* __restrict__ wa,
                                             unsigned short* __restrict__ waTb) {
    int idx = blockIdx.x * 256 + threadIdx.x;   // 0..4095
    int d = idx >> 6, k = idx & 63;
    waTb[idx] = f2bf(wa[k * 64 + d]);
}

// ---------------- K6: fused GEMM + mw + attention -----------------------------
// 1-D grid, bijective XCD swizzle (keeps A L2-resident per XCD: FETCH ~ Rb size).
// __launch_bounds__(256,4): cap total regs (VGPR+AGPR) at 128/wave -> 4 blocks/CU.
// All staging/fragment addresses hoisted out of the K loop (R3's regression was
// 84+64=148 regs -> 3 waves/SIMD; the extra 24 were per-iteration swizzle math).
// LDS XOR swizzle at 8-ushort granules: elem(r,k) -> r*64 + ((k>>3 ^ (r&7))<<3) + (k&7).
#define BM 128
#define NTY ((NN + BM - 1) / BM)   // 782
#define GEMM_NWG (NM * NTY)        // 10166

__global__ __launch_bounds__(256, 4) void k_gemm(const unsigned short* __restrict__ Rb,
                                                 const unsigned short* __restrict__ WT,
                                                 const unsigned short* __restrict__ waTb,
                                                 const float* __restrict__ ba,
                                                 const float* __restrict__ mb,
                                                 float* __restrict__ out) {
    const int nwg = GEMM_NWG, q = nwg >> 3, r = nwg & 7;   // q=1270, r=6
    int lin = blockIdx.x;
    int xcd = lin & 7, pos = lin >> 3;
    int v = (xcd < r ? xcd * (q + 1) : r * (q + 1) + (xcd - r) * q) + pos;
    int row_t = v / NM;
    int im1 = v - row_t * NM;      // 0..12, motif i = im1+1
    int i = im1 + 1;
    int row0 = row_t * BM;
    int t = threadIdx.x;
    int w = t >> 6;
    int lane = t & 63;
    int quad = lane >> 4;
    int l16 = lane & 15;

    __shared__ __align__(16) unsigned short Al[BM * 64];   // 16 KB
    __shared__ __align__(16) unsigned short Bl[64 * 64];   // 8 KB

    // ---- loop-invariant addressing (computed once) ----
    int aDst[4], aOffE[4];
    bool aOk[4];
#pragma unroll
    for (int s = 0; s < 4; ++s) {
        int l8 = t + s * 256, rr = l8 >> 3, g = l8 & 7;
        aDst[s]  = rr * 64 + ((g ^ (rr & 7)) << 3);
        aOffE[s] = (row0 + rr) * 64 + g * 8;
        aOk[s]   = (row0 + rr) < NN;
    }
    int bDst[2], bOffW[2], bOffT[2];
#pragma unroll
    for (int s = 0; s < 2; ++s) {
        int l8 = t + s * 256, n = l8 >> 3, g = l8 & 7;
        bDst[s]  = n * 64 + ((g ^ (n & 7)) << 3);
        bOffW[s] = n * 896 + g * 8;   // WT row stride 896
        bOffT[s] = n * 64 + g * 8;    // waTb row stride 64
    }
    int aRd[2], bRd[4];   // kk=0 fragment offsets; kk=32 is ^32 (swizzle XOR identity)
#pragma unroll
    for (int mt = 0; mt < 2; ++mt) {
        int ar = (w * 2 + mt) * 16 + l16;
        aRd[mt] = ar * 64 + ((quad ^ (ar & 7)) << 3);
    }
#pragma unroll
    for (int nt = 0; nt < 4; ++nt) {
        int br = nt * 16 + l16;
        bRd[nt] = br * 64 + ((quad ^ (br & 7)) << 3);
    }

    floatx4 acc[2][4];   // c accumulator: [m-tile][n-tile]
    floatx4 mwa[2][4];   // mw accumulator
#pragma unroll
    for (int a = 0; a < 2; ++a)
#pragma unroll
        for (int b = 0; b < 4; ++b) { acc[a][b] = (floatx4)0.f; mwa[a][b] = (floatx4)0.f; }

    const unsigned short* WTb = WT + (long long)im1 * 64 * 896;
    const long long chunkE = (long long)NN * 64;

    // ---- main K loop: c accumulation over chunks 0..13 ----
    for (int kb = 0; kb < 14; ++kb) {
        __syncthreads();
        const unsigned short* aSrc = Rb + (long long)kb * chunkE;
#pragma unroll
        for (int s = 0; s < 4; ++s) {
            short8 vv = (short8)0;
            if (aOk[s]) vv = *(const short8*)(aSrc + aOffE[s]);
            *(short8*)&Al[aDst[s]] = vv;
        }
        const unsigned short* bSrc = WTb + kb * 64;
#pragma unroll
        for (int s = 0; s < 2; ++s)
            *(short8*)&Bl[bDst[s]] = *(const short8*)(bSrc + bOffW[s]);
        __syncthreads();
#pragma unroll
        for (int h = 0; h < 2; ++h) {
            int x = h * 32;
            short8 af0 = *(const short8*)&Al[aRd[0] ^ x];
            short8 af1 = *(const short8*)&Al[aRd[1] ^ x];
#pragma unroll
            for (int nt = 0; nt < 4; ++nt) {
                short8 bf = *(const short8*)&Bl[bRd[nt] ^ x];
                acc[0][nt] = __builtin_amdgcn_mfma_f32_16x16x32_bf16(af0, bf, acc[0][nt], 0, 0, 0);
                acc[1][nt] = __builtin_amdgcn_mfma_f32_16x16x32_bf16(af1, bf, acc[1][nt], 0, 0, 0);
            }
        }
    }

    // ---- mw pass: A = chunk i, B = waT ----
    {
        __syncthreads();
        const unsigned short* aSrc = Rb + (long long)i * chunkE;
#pragma unroll
        for (int s = 0; s < 4; ++s) {
            short8 vv = (short8)0;
            if (aOk[s]) vv = *(const short8*)(aSrc + aOffE[s]);
            *(short8*)&Al[aDst[s]] = vv;
        }
#pragma unroll
        for (int s = 0; s < 2; ++s)
            *(short8*)&Bl[bDst[s]] = *(const short8*)(waTb + bOffT[s]);
        __syncthreads();
#pragma unroll
        for (int h = 0; h < 2; ++h) {
            int x = h * 32;
            short8 af0 = *(const short8*)&Al[aRd[0] ^ x];
            short8 af1 = *(const short8*)&Al[aRd[1] ^ x];
#pragma unroll
            for (int nt = 0; nt < 4; ++nt) {
                short8 bf = *(const short8*)&Bl[bRd[nt] ^ x];
                mwa[0][nt] = __builtin_amdgcn_mfma_f32_16x16x32_bf16(af0, bf, mwa[0][nt], 0, 0, 0);
                mwa[1][nt] = __builtin_amdgcn_mfma_f32_16x16x32_bf16(af1, bf, mwa[1][nt], 0, 0, 0);
            }
        }
    }

    // epilogue: c += mb, mw += ba; att = sigmoid(sum_d mw*c); out = att*(mw-c)
#pragma unroll
    for (int mt = 0; mt < 2; ++mt) {
        float cv[4][4], mv[4][4];   // [nt][reg]
#pragma unroll
        for (int nt = 0; nt < 4; ++nt) {
            int col = nt * 16 + l16;
            float mbv = mb[im1 * 64 + col];
            float bav = ba[col];
#pragma unroll
            for (int r2 = 0; r2 < 4; ++r2) {
                cv[nt][r2] = acc[mt][nt][r2] + mbv;
                mv[nt][r2] = mwa[mt][nt][r2] + bav;
            }
        }
        int grow_base = row0 + (w * 2 + mt) * 16 + quad * 4;
#pragma unroll
        for (int r2 = 0; r2 < 4; ++r2) {
            float s = 0.f;
#pragma unroll
            for (int nt = 0; nt < 4; ++nt) s += mv[nt][r2] * cv[nt][r2];
            s += __shfl_xor(s, 1);
            s += __shfl_xor(s, 2);
            s += __shfl_xor(s, 4);
            s += __shfl_xor(s, 8);   // full 64-col row sum within the 16-lane quad group
            float att = 1.f / (1.f + __expf(-s));
            int grow = grow_base + r2;
            if (grow < NN) {
#pragma unroll
                for (int nt = 0; nt < 4; ++nt)
                    out[(long long)grow * 832 + im1 * 64 + nt * 16 + l16] = att * (mv[nt][r2] - cv[nt][r2]);
            }
        }
    }
}

// ------------------------------------------------------------------------------
extern "C" void kernel_launch(void* const* d_in, const int* in_sizes, int n_in,
                              void* d_out, int out_size, void* d_ws, size_t ws_size,
                              hipStream_t stream) {
    const float* x    = (const float*)d_in[0];
    const int*   ei   = (const int*)d_in[1];
    const float* ew   = (const float*)d_in[2];
    const int*   msrc = (const int*)d_in[3];
    const int*   mdst = (const int*)d_in[4];
    const float* mval = (const float*)d_in[5];
    const float* Wrel = (const float*)d_in[6];
    const float* root = (const float*)d_in[7];
    const float* bias = (const float*)d_in[8];
    const float* wa   = (const float*)d_in[9];
    const float* ba   = (const float*)d_in[10];
    const float* mW   = (const float*)d_in[11];
    const float* mb   = (const float*)d_in[12];
    float* out = (float*)d_out;

    // workspace layout (~345 MB)
    unsigned short* Rb = (unsigned short*)d_ws;                 // [14][NN][64] bf16 (chunk-major)
    float* H  = (float*)(Rb + (size_t)14 * NN * 64);            // [NN][64] fp32
    float* XW = H + (size_t)NN * 64;                            // [NN][64] fp32
    unsigned short* WT = (unsigned short*)(XW + (size_t)NN * 64); // [832][896] bf16
    unsigned short* waTb = WT + (size_t)832 * 896;              // [64][64] bf16
    int2* sm = (int2*)(waTb + (size_t)64 * 64);                 // [13][MNZ] {src,val}
    int2* se = sm + (size_t)NM * MNZ;                           // [NE] {src,w}
    int* cnt_m  = (int*)(se + NE);                              // [13][NN]
    int* cnt_e  = cnt_m + (size_t)NM * NN;                      // [NN]
    int* cursors = cnt_e + NN;                                  // [16]
    int* off_m  = cursors + 16;                                 // [13][NN]
    int* fill_m = off_m + (size_t)NM * NN;                      // [13][NN]
    int* off_e  = fill_m + (size_t)NM * NN;                     // [NN]
    int* fill_e = off_e + NN;                                   // [NN]

    // zero cnt_m + cnt_e + cursors in one shot (contiguous)
    hipMemsetAsync(cnt_m, 0, sizeof(int) * ((size_t)NM * NN + NN + 16), stream);

    k_xw<<<NN / 4, 256, 0, stream>>>(x, Wrel, XW);
    k_hist_m<<<dim3(MNZ / 256, NM), 256, 0, stream>>>(mdst, cnt_m);
    k_hist_e<<<NE / 256, 256, 0, stream>>>(ei, cnt_e);
    k_alloc<<<dim3((NN + 255) / 256, NM), 256, 0, stream>>>(cnt_m, off_m, fill_m, cursors, NN);
    k_alloc<<<dim3((NN + 255) / 256, 1), 256, 0, stream>>>(cnt_e, off_e, fill_e, cursors + NM, NN);
    k_scat_m<<<dim3((MNZ / 256) * 8, NM), 256, 0, stream>>>(msrc, mdst, mval, fill_m, sm);
    k_scat_e<<<(NE / 256) * 8, 256, 0, stream>>>(ei, ew, fill_e, se);
    k_gath_e<<<NN / 16, 256, 0, stream>>>(se, off_e, cnt_e, XW, H);
    k_fin<<<NN / 4, 256, 0, stream>>>(x, root, bias, cnt_e, H, Rb);
    k_gath_m<<<dim3(NN / 16, NM), 256, 0, stream>>>(sm, off_m, cnt_m, H, Rb);
    k_wt<<<dim3(7, 832), 128, 0, stream>>>(mW, WT);
    k_wat<<<16, 256, 0, stream>>>(wa, waTb);
    k_gemm<<<GEMM_NWG, 256, 0, stream>>>(Rb, WT, waTb, ba, mb, out);
}